// Round 1
// baseline (16762.437 us; speedup 1.0000x reference)
//
#include <hip/hip_runtime.h>
#include <hip/hip_bf16.h>
#include <stdint.h>
#include <stddef.h>

typedef __hip_bfloat16 bf16;
typedef __attribute__((ext_vector_type(8))) short bfrag;
typedef __attribute__((ext_vector_type(4))) float ffrag;

#define HDIM 1024
#define BATCH 64
#define TSTEPS 256
#define GDIM 4096
#define VOCAB 32000
#define NWG_SEQ 256

__device__ __forceinline__ float b2f(bf16 x) { return __bfloat162float(x); }
__device__ __forceinline__ bf16 f2b(float x) { return __float2bfloat16(x); }
__device__ __forceinline__ short f2bs(float x) {
  bf16 b = __float2bfloat16(x);
  return *reinterpret_cast<short*>(&b);
}
__device__ __forceinline__ ffrag mfma16(bfrag a, bfrag b, ffrag c) {
  return __builtin_amdgcn_mfma_f32_16x16x32_bf16(a, b, c, 0, 0, 0);
}
__device__ __forceinline__ float sigm(float x) { return 1.0f / (1.0f + __expf(-x)); }
__device__ __forceinline__ float tanhfast(float x) {
  float e = __expf(2.0f * x);
  return 1.0f - 2.0f / (e + 1.0f);
}

// ---------------- convert f32 -> bf16 ----------------
__global__ void convert_bf16_kernel(const float* __restrict__ src, bf16* __restrict__ dst, int n4) {
  int i = blockIdx.x * 256 + threadIdx.x;
  if (i >= n4) return;
  float4 v = reinterpret_cast<const float4*>(src)[i];
  ushort4 o;
  o.x = (unsigned short)f2bs(v.x);
  o.y = (unsigned short)f2bs(v.y);
  o.z = (unsigned short)f2bs(v.z);
  o.w = (unsigned short)f2bs(v.w);
  reinterpret_cast<ushort4*>(dst)[i] = o;
}

// ---------------- embedding gather -> bf16 ----------------
__global__ void embed_kernel(const int* __restrict__ ids, const float* __restrict__ table,
                             bf16* __restrict__ x, int n4) {
  int i = blockIdx.x * 256 + threadIdx.x;
  if (i >= n4) return;
  int row = i >> 8;   // H/4 = 256 float4 per (b,t) row
  int c4 = i & 255;
  int tok = ids[row];
  float4 v = reinterpret_cast<const float4*>(table)[(size_t)tok * 256 + c4];
  ushort4 o;
  o.x = (unsigned short)f2bs(v.x);
  o.y = (unsigned short)f2bs(v.y);
  o.z = (unsigned short)f2bs(v.z);
  o.w = (unsigned short)f2bs(v.w);
  reinterpret_cast<ushort4*>(x)[i] = o;
}

// ---------------- xg = x @ W_ih^T + b_ih + b_hh ----------------
// A: (16384,1024) bf16 K-major; W: (4096,1024) bf16 K-major; out xg: (T,B,4096) bf16
#define BMX 128
#define BNX 128
#define BKX 64

__launch_bounds__(256, 2)
__global__ void gemm_xg_kernel(const bf16* __restrict__ A,
                               const bf16* __restrict__ W,
                               const float* __restrict__ bih,
                               const float* __restrict__ bhh,
                               bf16* __restrict__ xg) {
  __shared__ bf16 As[BMX][BKX + 8];
  __shared__ bf16 Bs[BNX][BKX + 8];
  const int n0 = blockIdx.x * BNX;
  const int m0 = blockIdx.y * BMX;
  const int tid = threadIdx.x;
  const int w = tid >> 6, l = tid & 63;
  const int wm = (w >> 1) * 64, wn = (w & 1) * 64;
  const int lr = l & 15, lk = (l >> 4) * 8;

  ffrag acc[4][4];
#pragma unroll
  for (int i = 0; i < 4; ++i)
#pragma unroll
    for (int j = 0; j < 4; ++j) acc[i][j] = ffrag{0.f, 0.f, 0.f, 0.f};

  const int sr = tid >> 1, sh = (tid & 1) * 32;
  for (int kb = 0; kb < HDIM; kb += BKX) {
    __syncthreads();
    {
      const uint4* ga = reinterpret_cast<const uint4*>(&A[(size_t)(m0 + sr) * HDIM + kb + sh]);
      uint4* la = reinterpret_cast<uint4*>(&As[sr][sh]);
      la[0] = ga[0]; la[1] = ga[1]; la[2] = ga[2]; la[3] = ga[3];
      const uint4* gb = reinterpret_cast<const uint4*>(&W[(size_t)(n0 + sr) * HDIM + kb + sh]);
      uint4* lb = reinterpret_cast<uint4*>(&Bs[sr][sh]);
      lb[0] = gb[0]; lb[1] = gb[1]; lb[2] = gb[2]; lb[3] = gb[3];
    }
    __syncthreads();
#pragma unroll
    for (int ks = 0; ks < 2; ++ks) {
      const int ko = ks * 32 + lk;
      bfrag af[4], bfv[4];
#pragma unroll
      for (int i = 0; i < 4; ++i)
        af[i] = *reinterpret_cast<const bfrag*>(&As[wm + i * 16 + lr][ko]);
#pragma unroll
      for (int j = 0; j < 4; ++j)
        bfv[j] = *reinterpret_cast<const bfrag*>(&Bs[wn + j * 16 + lr][ko]);
#pragma unroll
      for (int i = 0; i < 4; ++i)
#pragma unroll
        for (int j = 0; j < 4; ++j)
          acc[i][j] = mfma16(af[i], bfv[j], acc[i][j]);
    }
  }
  const int rg = (l >> 4) * 4;
#pragma unroll
  for (int j = 0; j < 4; ++j) {
    const int n = n0 + wn + j * 16 + lr;
    const float bias = bih[n] + bhh[n];
#pragma unroll
    for (int i = 0; i < 4; ++i) {
#pragma unroll
      for (int r = 0; r < 4; ++r) {
        const int m = m0 + wm + i * 16 + rg + r;
        const int b = m >> 8, t = m & 255;   // m = b*256 + t
        xg[((size_t)t * BATCH + b) * GDIM + n] = f2b(acc[i][j][r] + bias);
      }
    }
  }
}

// ---------------- grid barrier (monotonic counter) ----------------
__device__ __forceinline__ void grid_barrier(unsigned* cnt, unsigned target) {
  __syncthreads();
  if (threadIdx.x == 0) {
    __threadfence();   // release: flush this XCD's L2 (covers all waves' completed stores)
    __hip_atomic_fetch_add(cnt, 1u, __ATOMIC_RELEASE, __HIP_MEMORY_SCOPE_AGENT);
    while (__hip_atomic_load(cnt, __ATOMIC_RELAXED, __HIP_MEMORY_SCOPE_AGENT) < target)
      __builtin_amdgcn_s_sleep(1);
    __threadfence();   // acquire: invalidate L1/L2 before re-reading h
  }
  __syncthreads();
}

// ---------------- persistent LSTM recurrence ----------------
// 256 WGs; WG k owns hidden positions j0=4k..4k+3 => 16 gate columns {q*1024+j0+jj}.
__launch_bounds__(256, 1)
__global__ void lstm_seq_kernel(const bf16* __restrict__ xg,   // (T,B,4096)
                                const bf16* __restrict__ Whh,  // (4096,1024) bf16
                                float* __restrict__ cst,       // (64,1024) f32 state
                                bf16* __restrict__ h0,         // ping
                                bf16* __restrict__ h1,         // pong
                                bf16* __restrict__ ys,         // (B,T,H) layer output
                                float* __restrict__ out_h,
                                float* __restrict__ out_c,
                                float* __restrict__ out_last,  // null except last layer
                                unsigned* __restrict__ cnt) {
  __shared__ bf16 lw[16][HDIM + 8];   // W_hh rows for the 16 gate cols (padded)
  __shared__ float gx[4][16][17];     // per-wave gate exchange
  const int wg = blockIdx.x;
  const int tid = threadIdx.x;
  const int w = tid >> 6, l = tid & 63;
  const int j0 = wg * 4;

  // stage this WG's 16 W_hh rows into LDS (once)
#pragma unroll
  for (int pp = 0; pp < 4; ++pp) {
    const int p = pp * 4 + w;
    const int gcol = (p >> 2) * HDIM + j0 + (p & 3);
    const uint4* src = reinterpret_cast<const uint4*>(&Whh[(size_t)gcol * HDIM]);
    uint4* dst = reinterpret_cast<uint4*>(&lw[p][0]);
    dst[l] = src[l];
    dst[l + 64] = src[l + 64];
  }
  // init owned c and h0 slices
  {
    const int b = tid >> 2, j = j0 + (tid & 3);
    cst[b * HDIM + j] = 0.0f;
    h0[b * HDIM + j] = f2b(0.0f);
  }
  grid_barrier(cnt, NWG_SEQ);

  const int lr = l & 15, lk = (l >> 4) * 8;
  const int arow_b = 16 * w + lr;          // batch row for A-fragments
  const int p = lr;                        // gate-col slot
  const int gcol = (p >> 2) * HDIM + j0 + (p & 3);
  const int bl = l >> 2, jj = l & 3;       // update assignment
  const int b_upd = 16 * w + bl, j_upd = j0 + jj;

  for (int t = 0; t < TSTEPS; ++t) {
    const bf16* hin = (t & 1) ? h1 : h0;
    bf16* hout = (t & 1) ? h0 : h1;
    ffrag acc0 = ffrag{0.f, 0.f, 0.f, 0.f};
    ffrag acc1 = ffrag{0.f, 0.f, 0.f, 0.f};
    const bf16* hrow = &hin[(size_t)arow_b * HDIM];
#pragma unroll 4
    for (int ks = 0; ks < 32; ks += 2) {
      bfrag a0 = *reinterpret_cast<const bfrag*>(&hrow[ks * 32 + lk]);
      bfrag b0 = *reinterpret_cast<const bfrag*>(&lw[p][ks * 32 + lk]);
      acc0 = mfma16(a0, b0, acc0);
      bfrag a1 = *reinterpret_cast<const bfrag*>(&hrow[ks * 32 + 32 + lk]);
      bfrag b1 = *reinterpret_cast<const bfrag*>(&lw[p][ks * 32 + 32 + lk]);
      acc1 = mfma16(a1, b1, acc1);
    }
    ffrag acc = acc0 + acc1;
    const bf16* xgt = xg + (size_t)t * BATCH * GDIM;
#pragma unroll
    for (int r = 0; r < 4; ++r) {
      const int b = 16 * w + (l >> 4) * 4 + r;
      gx[w][(l >> 4) * 4 + r][p] = acc[r] + b2f(xgt[(size_t)b * GDIM + gcol]);
    }
    __syncthreads();
    {
      const float gi = gx[w][bl][0 + jj];
      const float gf = gx[w][bl][4 + jj];
      const float gg = gx[w][bl][8 + jj];
      const float go = gx[w][bl][12 + jj];
      const float iv = sigm(gi), fv = sigm(gf), gv = tanhfast(gg), ov = sigm(go);
      const float c_old = cst[b_upd * HDIM + j_upd];
      const float c_new = fv * c_old + iv * gv;
      const float h_new = ov * tanhfast(c_new);
      cst[b_upd * HDIM + j_upd] = c_new;
      hout[b_upd * HDIM + j_upd] = f2b(h_new);
      ys[((size_t)b_upd * TSTEPS + t) * HDIM + j_upd] = f2b(h_new);
      if (t == TSTEPS - 1) {
        out_h[b_upd * HDIM + j_upd] = h_new;
        out_c[b_upd * HDIM + j_upd] = c_new;
        if (out_last) out_last[b_upd * HDIM + j_upd] = h_new;
      }
    }
    if (t + 1 < TSTEPS) grid_barrier(cnt, (unsigned)(t + 2) * NWG_SEQ);
  }
}

// ---------------- logits = h_T @ W_proj^T + b_proj ----------------
__launch_bounds__(256, 2)
__global__ void logits_kernel(const bf16* __restrict__ hfin,  // (64,1024) bf16
                              const float* __restrict__ Wp,   // (32000,1024) f32
                              const float* __restrict__ bp,
                              float* __restrict__ out) {      // (64,32000)
  const int tid = threadIdx.x;
  const int w = tid >> 6, l = tid & 63;
  const int lr = l & 15, lk = (l >> 4) * 8;
  const int col = blockIdx.x * 64 + w * 16 + lr;
  const float* wrow = &Wp[(size_t)col * HDIM];
  ffrag acc[4];
#pragma unroll
  for (int i = 0; i < 4; ++i) acc[i] = ffrag{0.f, 0.f, 0.f, 0.f};
#pragma unroll 2
  for (int ks = 0; ks < 32; ++ks) {
    const int k = ks * 32 + lk;
    float4 wa = *reinterpret_cast<const float4*>(&wrow[k]);
    float4 wb = *reinterpret_cast<const float4*>(&wrow[k + 4]);
    bfrag bv;
    bv[0] = f2bs(wa.x); bv[1] = f2bs(wa.y); bv[2] = f2bs(wa.z); bv[3] = f2bs(wa.w);
    bv[4] = f2bs(wb.x); bv[5] = f2bs(wb.y); bv[6] = f2bs(wb.z); bv[7] = f2bs(wb.w);
#pragma unroll
    for (int i = 0; i < 4; ++i) {
      bfrag av = *reinterpret_cast<const bfrag*>(&hfin[(size_t)(i * 16 + lr) * HDIM + k]);
      acc[i] = mfma16(av, bv, acc[i]);
    }
  }
  const float bias = bp[col];
#pragma unroll
  for (int i = 0; i < 4; ++i) {
#pragma unroll
    for (int r = 0; r < 4; ++r) {
      const int b = i * 16 + (l >> 4) * 4 + r;
      out[(size_t)b * VOCAB + col] = acc[i][r] + bias;
    }
  }
}

extern "C" void kernel_launch(void* const* d_in, const int* in_sizes, int n_in,
                              void* d_out, int out_size, void* d_ws, size_t ws_size,
                              hipStream_t stream) {
  const int*   ids   = (const int*)d_in[0];
  const float* table = (const float*)d_in[1];
  const float* Wih   = (const float*)d_in[2];
  const float* Whh   = (const float*)d_in[3];
  const float* bih   = (const float*)d_in[4];
  const float* bhh   = (const float*)d_in[5];
  const float* Wp    = (const float*)d_in[6];
  const float* bp    = (const float*)d_in[7];
  float* out = (float*)d_out;

  char* ws = (char*)d_ws;
  const size_t OFF_XG  = 0;                                              // 134,217,728 B
  const size_t OFF_X   = OFF_XG  + (size_t)TSTEPS * BATCH * GDIM * 2;    // +33,554,432
  const size_t OFF_WIH = OFF_X   + (size_t)BATCH * TSTEPS * HDIM * 2;    // +16,777,216
  const size_t OFF_WHH = OFF_WIH + (size_t)2 * GDIM * HDIM * 2;          // +16,777,216
  const size_t OFF_C   = OFF_WHH + (size_t)2 * GDIM * HDIM * 2;          // +262,144
  const size_t OFF_H0  = OFF_C   + (size_t)BATCH * HDIM * 4;             // +131,072
  const size_t OFF_H1  = OFF_H0  + (size_t)BATCH * HDIM * 2;             // +131,072
  const size_t OFF_CNT = OFF_H1  + (size_t)BATCH * HDIM * 2;             // +256

  bf16* xg    = (bf16*)(ws + OFF_XG);
  bf16* xb    = (bf16*)(ws + OFF_X);
  bf16* wihb  = (bf16*)(ws + OFF_WIH);
  bf16* whhb  = (bf16*)(ws + OFF_WHH);
  float* cst  = (float*)(ws + OFF_C);
  bf16* h0    = (bf16*)(ws + OFF_H0);
  bf16* h1    = (bf16*)(ws + OFF_H1);
  unsigned* cnt = (unsigned*)(ws + OFF_CNT);

  (void)hipMemsetAsync(cnt, 0, 256, stream);

  const int nconv4 = 2 * GDIM * HDIM / 4;  // 2,097,152
  convert_bf16_kernel<<<nconv4 / 256, 256, 0, stream>>>(Wih, wihb, nconv4);
  convert_bf16_kernel<<<nconv4 / 256, 256, 0, stream>>>(Whh, whhb, nconv4);
  const int nemb4 = BATCH * TSTEPS * HDIM / 4;  // 4,194,304
  embed_kernel<<<nemb4 / 256, 256, 0, stream>>>(ids, table, xb, nemb4);

  float* out_last   = out;              // (64,1024)
  float* out_logits = out + 65536;      // (64,32000)
  float* out_hn     = out + 2113536;    // (2,64,1024)
  float* out_cn     = out + 2244608;    // (2,64,1024)

  for (int lyr = 0; lyr < 2; ++lyr) {
    gemm_xg_kernel<<<dim3(GDIM / BNX, (BATCH * TSTEPS) / BMX), 256, 0, stream>>>(
        xb, wihb + (size_t)lyr * GDIM * HDIM, bih + lyr * GDIM, bhh + lyr * GDIM, xg);
    lstm_seq_kernel<<<NWG_SEQ, 256, 0, stream>>>(
        xg, whhb + (size_t)lyr * GDIM * HDIM, cst, h0, h1, xb,
        out_hn + (size_t)lyr * BATCH * HDIM, out_cn + (size_t)lyr * BATCH * HDIM,
        (lyr == 1) ? out_last : nullptr, cnt + lyr * 32);
  }
  logits_kernel<<<VOCAB / 64, 256, 0, stream>>>(h0, Wp, bp, out_logits);
}

// Round 2
// 9264.445 us; speedup vs baseline: 1.8093x; 1.8093x over previous
//
#include <hip/hip_runtime.h>
#include <hip/hip_bf16.h>
#include <stdint.h>
#include <stddef.h>

typedef __hip_bfloat16 bf16;
typedef __attribute__((ext_vector_type(8))) short bfrag;
typedef __attribute__((ext_vector_type(4))) float ffrag;

#define HDIM 1024
#define BATCH 64
#define TSTEPS 256
#define GDIM 4096
#define VOCAB 32000
#define NWG_SEQ 128   // 128 WGs x 512 threads; WG owns 8 hidden cols (32 gate cols)

__device__ __forceinline__ float b2f(bf16 x) { return __bfloat162float(x); }
__device__ __forceinline__ bf16 f2b(float x) { return __float2bfloat16(x); }
__device__ __forceinline__ short f2bs(float x) {
  bf16 b = __float2bfloat16(x);
  return *reinterpret_cast<short*>(&b);
}
__device__ __forceinline__ ffrag mfma16(bfrag a, bfrag b, ffrag c) {
  return __builtin_amdgcn_mfma_f32_16x16x32_bf16(a, b, c, 0, 0, 0);
}
__device__ __forceinline__ float sigm(float x) { return 1.0f / (1.0f + __expf(-x)); }
__device__ __forceinline__ float tanhfast(float x) {
  float e = __expf(2.0f * x);
  return 1.0f - 2.0f / (e + 1.0f);
}

// ---------------- convert f32 -> bf16 ----------------
__global__ void convert_bf16_kernel(const float* __restrict__ src, bf16* __restrict__ dst, int n4) {
  int i = blockIdx.x * 256 + threadIdx.x;
  if (i >= n4) return;
  float4 v = reinterpret_cast<const float4*>(src)[i];
  ushort4 o;
  o.x = (unsigned short)f2bs(v.x);
  o.y = (unsigned short)f2bs(v.y);
  o.z = (unsigned short)f2bs(v.z);
  o.w = (unsigned short)f2bs(v.w);
  reinterpret_cast<ushort4*>(dst)[i] = o;
}

// ---------------- embedding gather -> bf16 ----------------
__global__ void embed_kernel(const int* __restrict__ ids, const float* __restrict__ table,
                             bf16* __restrict__ x, int n4) {
  int i = blockIdx.x * 256 + threadIdx.x;
  if (i >= n4) return;
  int row = i >> 8;   // H/4 = 256 float4 per (b,t) row
  int c4 = i & 255;
  int tok = ids[row];
  float4 v = reinterpret_cast<const float4*>(table)[(size_t)tok * 256 + c4];
  ushort4 o;
  o.x = (unsigned short)f2bs(v.x);
  o.y = (unsigned short)f2bs(v.y);
  o.z = (unsigned short)f2bs(v.z);
  o.w = (unsigned short)f2bs(v.w);
  reinterpret_cast<ushort4*>(x)[i] = o;
}

// ---------------- xg = x @ W_ih^T + b_ih + b_hh ----------------
// A: (16384,1024) bf16 K-major; W: (4096,1024) bf16 K-major.
// out xg layout: (wg, t, b, 32) -- per-recurrence-WG contiguous.
#define BMX 128
#define BNX 128
#define BKX 64

__launch_bounds__(256, 2)
__global__ void gemm_xg_kernel(const bf16* __restrict__ A,
                               const bf16* __restrict__ W,
                               const float* __restrict__ bih,
                               const float* __restrict__ bhh,
                               bf16* __restrict__ xg) {
  __shared__ bf16 As[BMX][BKX + 8];
  __shared__ bf16 Bs[BNX][BKX + 8];
  const int n0 = blockIdx.x * BNX;
  const int m0 = blockIdx.y * BMX;
  const int tid = threadIdx.x;
  const int w = tid >> 6, l = tid & 63;
  const int wm = (w >> 1) * 64, wn = (w & 1) * 64;
  const int lr = l & 15, lk = (l >> 4) * 8;

  ffrag acc[4][4];
#pragma unroll
  for (int i = 0; i < 4; ++i)
#pragma unroll
    for (int j = 0; j < 4; ++j) acc[i][j] = ffrag{0.f, 0.f, 0.f, 0.f};

  const int sr = tid >> 1, sh = (tid & 1) * 32;
  for (int kb = 0; kb < HDIM; kb += BKX) {
    __syncthreads();
    {
      const uint4* ga = reinterpret_cast<const uint4*>(&A[(size_t)(m0 + sr) * HDIM + kb + sh]);
      uint4* la = reinterpret_cast<uint4*>(&As[sr][sh]);
      la[0] = ga[0]; la[1] = ga[1]; la[2] = ga[2]; la[3] = ga[3];
      const uint4* gb = reinterpret_cast<const uint4*>(&W[(size_t)(n0 + sr) * HDIM + kb + sh]);
      uint4* lb = reinterpret_cast<uint4*>(&Bs[sr][sh]);
      lb[0] = gb[0]; lb[1] = gb[1]; lb[2] = gb[2]; lb[3] = gb[3];
    }
    __syncthreads();
#pragma unroll
    for (int ks = 0; ks < 2; ++ks) {
      const int ko = ks * 32 + lk;
      bfrag af[4], bfv[4];
#pragma unroll
      for (int i = 0; i < 4; ++i)
        af[i] = *reinterpret_cast<const bfrag*>(&As[wm + i * 16 + lr][ko]);
#pragma unroll
      for (int j = 0; j < 4; ++j)
        bfv[j] = *reinterpret_cast<const bfrag*>(&Bs[wn + j * 16 + lr][ko]);
#pragma unroll
      for (int i = 0; i < 4; ++i)
#pragma unroll
        for (int j = 0; j < 4; ++j)
          acc[i][j] = mfma16(af[i], bfv[j], acc[i][j]);
    }
  }
  const int rg = (l >> 4) * 4;
#pragma unroll
  for (int j = 0; j < 4; ++j) {
    const int n = n0 + wn + j * 16 + lr;
    const float bias = bih[n] + bhh[n];
    const int g = (n & 1023) >> 3;                 // owning recurrence WG
    const int p = ((n >> 10) << 3) | (n & 7);      // slot within WG's 32 cols
    bf16* base = xg + (size_t)g * TSTEPS * BATCH * 32;
#pragma unroll
    for (int i = 0; i < 4; ++i) {
#pragma unroll
      for (int r = 0; r < 4; ++r) {
        const int m = m0 + wm + i * 16 + rg + r;
        const int b = m >> 8, t = m & 255;   // m = b*256 + t
        base[((size_t)t * BATCH + b) * 32 + p] = f2b(acc[i][j][r] + bias);
      }
    }
  }
}

// ---------------- flag-tree grid barrier (no atomics) ----------------
// flags[wg*32]: per-WG epoch flag (128B stride). go: separate line.
__device__ __forceinline__ void gbar(unsigned* flags, unsigned* go, unsigned ep, int wg, int tid) {
  __syncthreads();
  if (tid == 0) {
    __threadfence();   // release: drain this WG's stores to device scope
    __hip_atomic_store(&flags[wg * 32], ep, __ATOMIC_RELEASE, __HIP_MEMORY_SCOPE_AGENT);
  }
  if (wg == 0 && tid < 64) {
    // master wave: each lane owns 2 flags, polls until both reach ep
    for (;;) {
      unsigned v = __hip_atomic_load(&flags[tid * 32], __ATOMIC_RELAXED, __HIP_MEMORY_SCOPE_AGENT);
      if (v >= ep) break;
      __builtin_amdgcn_s_sleep(2);
    }
    for (;;) {
      unsigned v = __hip_atomic_load(&flags[(tid + 64) * 32], __ATOMIC_RELAXED, __HIP_MEMORY_SCOPE_AGENT);
      if (v >= ep) break;
      __builtin_amdgcn_s_sleep(2);
    }
    if (tid == 0) {
      __threadfence();
      __hip_atomic_store(go, ep, __ATOMIC_RELEASE, __HIP_MEMORY_SCOPE_AGENT);
    }
  }
  if (tid == 0) {
    while (__hip_atomic_load(go, __ATOMIC_RELAXED, __HIP_MEMORY_SCOPE_AGENT) < ep)
      __builtin_amdgcn_s_sleep(4);
    __threadfence();   // acquire: invalidate caches before re-reading h
  }
  __syncthreads();
}

// ---------------- persistent LSTM recurrence ----------------
// 128 WGs x 512 threads. WG g owns hidden cols j0=8g..8g+7 => 32 gate cols
// (slot p: q = p>>3, jj = p&7 -> gcol = q*1024 + j0 + jj).
__launch_bounds__(512, 1)
__global__ void lstm_seq_kernel(const bf16* __restrict__ xg,   // (wg,t,b,32)
                                const bf16* __restrict__ Whh,  // (4096,1024) bf16
                                bf16* h0, bf16* h1,            // ping-pong h
                                bf16* __restrict__ ys,         // (B,T,H) layer output
                                float* __restrict__ out_h,
                                float* __restrict__ out_c,
                                float* __restrict__ out_last,  // null except last layer
                                unsigned* __restrict__ flags,
                                unsigned* __restrict__ go) {
  __shared__ bf16 lw[32][HDIM + 8];   // W_hh rows for the 32 gate cols
  __shared__ float gx[BATCH][36];     // gate exchange (batch x 32, padded)
  const int wg = blockIdx.x;
  const int tid = threadIdx.x;
  const int w = tid >> 6, l = tid & 63;
  const int j0 = wg * 8;

  // stage this WG's 32 W_hh rows into LDS (once)
  {
    const int p = tid >> 4, li = tid & 15;
    const int gcol = (p >> 3) * HDIM + j0 + (p & 7);
    const uint4* src = reinterpret_cast<const uint4*>(&Whh[(size_t)gcol * HDIM]);
    uint4* dst = reinterpret_cast<uint4*>(&lw[p][0]);
#pragma unroll
    for (int kk = 0; kk < 8; ++kk) dst[li + kk * 16] = src[li + kk * 16];
  }
  // per-thread cell-state ownership: (b_upd, j_upd)
  const int b_upd = tid >> 3, jj = tid & 7, j_upd = j0 + jj;
  h0[b_upd * HDIM + j_upd] = f2b(0.0f);
  float c_reg = 0.0f;

  gbar(flags, go, 1u, wg, tid);

  const int lr = l & 15, lk = (l >> 4) * 8;
  const int wm = w >> 1;                 // batch group 0..3
  const int pl = (w & 1) * 16 + lr;      // gate-col slot 0..31
  const int rg = (l >> 4) * 4;
  const bf16* xgw = xg + (size_t)wg * TSTEPS * BATCH * 32;

  for (int t = 0; t < TSTEPS; ++t) {
    const bf16* hin = (t & 1) ? h1 : h0;
    bf16* hout = (t & 1) ? h0 : h1;
    ffrag a0 = ffrag{0.f, 0.f, 0.f, 0.f};
    ffrag a1 = ffrag{0.f, 0.f, 0.f, 0.f};
    const bf16* hrow = &hin[(size_t)(16 * wm + lr) * HDIM];
#pragma unroll 4
    for (int ks = 0; ks < 32; ks += 2) {
      bfrag x0 = *reinterpret_cast<const bfrag*>(&hrow[ks * 32 + lk]);
      bfrag w0 = *reinterpret_cast<const bfrag*>(&lw[pl][ks * 32 + lk]);
      a0 = mfma16(x0, w0, a0);
      bfrag x1 = *reinterpret_cast<const bfrag*>(&hrow[ks * 32 + 32 + lk]);
      bfrag w1 = *reinterpret_cast<const bfrag*>(&lw[pl][ks * 32 + 32 + lk]);
      a1 = mfma16(x1, w1, a1);
    }
    ffrag acc = a0 + a1;
    const bf16* xgt = xgw + (size_t)t * BATCH * 32;
#pragma unroll
    for (int r = 0; r < 4; ++r) {
      const int b = 16 * wm + rg + r;
      gx[b][pl] = acc[r] + b2f(xgt[b * 32 + pl]);
    }
    __syncthreads();
    {
      const float gi = gx[b_upd][0 * 8 + jj];
      const float gf = gx[b_upd][1 * 8 + jj];
      const float gg = gx[b_upd][2 * 8 + jj];
      const float gov = gx[b_upd][3 * 8 + jj];
      const float iv = sigm(gi), fv = sigm(gf), gv = tanhfast(gg), ov = sigm(gov);
      c_reg = fv * c_reg + iv * gv;
      const float h_new = ov * tanhfast(c_reg);
      hout[b_upd * HDIM + j_upd] = f2b(h_new);
      ys[((size_t)b_upd * TSTEPS + t) * HDIM + j_upd] = f2b(h_new);
      if (t == TSTEPS - 1) {
        out_h[b_upd * HDIM + j_upd] = h_new;
        out_c[b_upd * HDIM + j_upd] = c_reg;
        if (out_last) out_last[b_upd * HDIM + j_upd] = h_new;
      }
    }
    if (t + 1 < TSTEPS) gbar(flags, go, (unsigned)(t + 2), wg, tid);
  }
}

// ---------------- logits = h_T @ W_proj^T + b_proj ----------------
__launch_bounds__(256, 2)
__global__ void logits_kernel(const bf16* __restrict__ hfin,  // (64,1024) bf16
                              const float* __restrict__ Wp,   // (32000,1024) f32
                              const float* __restrict__ bp,
                              float* __restrict__ out) {      // (64,32000)
  const int tid = threadIdx.x;
  const int w = tid >> 6, l = tid & 63;
  const int lr = l & 15, lk = (l >> 4) * 8;
  const int col = blockIdx.x * 64 + w * 16 + lr;
  const float* wrow = &Wp[(size_t)col * HDIM];
  ffrag acc[4];
#pragma unroll
  for (int i = 0; i < 4; ++i) acc[i] = ffrag{0.f, 0.f, 0.f, 0.f};
#pragma unroll 2
  for (int ks = 0; ks < 32; ++ks) {
    const int k = ks * 32 + lk;
    float4 wa = *reinterpret_cast<const float4*>(&wrow[k]);
    float4 wb = *reinterpret_cast<const float4*>(&wrow[k + 4]);
    bfrag bv;
    bv[0] = f2bs(wa.x); bv[1] = f2bs(wa.y); bv[2] = f2bs(wa.z); bv[3] = f2bs(wa.w);
    bv[4] = f2bs(wb.x); bv[5] = f2bs(wb.y); bv[6] = f2bs(wb.z); bv[7] = f2bs(wb.w);
#pragma unroll
    for (int i = 0; i < 4; ++i) {
      bfrag av = *reinterpret_cast<const bfrag*>(&hfin[(size_t)(i * 16 + lr) * HDIM + k]);
      acc[i] = mfma16(av, bv, acc[i]);
    }
  }
  const float bias = bp[col];
#pragma unroll
  for (int i = 0; i < 4; ++i) {
#pragma unroll
    for (int r = 0; r < 4; ++r) {
      const int b = i * 16 + (l >> 4) * 4 + r;
      out[(size_t)b * VOCAB + col] = acc[i][r] + bias;
    }
  }
}

extern "C" void kernel_launch(void* const* d_in, const int* in_sizes, int n_in,
                              void* d_out, int out_size, void* d_ws, size_t ws_size,
                              hipStream_t stream) {
  const int*   ids   = (const int*)d_in[0];
  const float* table = (const float*)d_in[1];
  const float* Wih   = (const float*)d_in[2];
  const float* Whh   = (const float*)d_in[3];
  const float* bih   = (const float*)d_in[4];
  const float* bhh   = (const float*)d_in[5];
  const float* Wp    = (const float*)d_in[6];
  const float* bp    = (const float*)d_in[7];
  float* out = (float*)d_out;

  char* ws = (char*)d_ws;
  const size_t OFF_XG  = 0;                                              // 134,217,728 B
  const size_t OFF_X   = OFF_XG  + (size_t)NWG_SEQ * TSTEPS * BATCH * 32 * 2;  // +134,217,728
  const size_t OFF_WIH = OFF_X   + (size_t)BATCH * TSTEPS * HDIM * 2;    // +33,554,432
  const size_t OFF_WHH = OFF_WIH + (size_t)2 * GDIM * HDIM * 2;          // +16,777,216
  const size_t OFF_SYNC= OFF_WHH + (size_t)2 * GDIM * HDIM * 2;          // +16,777,216
  const size_t OFF_H0  = OFF_SYNC+ (size_t)65536;
  const size_t OFF_H1  = OFF_H0  + (size_t)BATCH * HDIM * 2;

  bf16* xg    = (bf16*)(ws + OFF_XG);
  bf16* xb    = (bf16*)(ws + OFF_X);
  bf16* wihb  = (bf16*)(ws + OFF_WIH);
  bf16* whhb  = (bf16*)(ws + OFF_WHH);
  unsigned* sync = (unsigned*)(ws + OFF_SYNC);
  bf16* h0    = (bf16*)(ws + OFF_H0);
  bf16* h1    = (bf16*)(ws + OFF_H1);

  (void)hipMemsetAsync(sync, 0, 65536, stream);

  const int nconv4 = 2 * GDIM * HDIM / 4;  // 2,097,152
  convert_bf16_kernel<<<nconv4 / 256, 256, 0, stream>>>(Wih, wihb, nconv4);
  convert_bf16_kernel<<<nconv4 / 256, 256, 0, stream>>>(Whh, whhb, nconv4);
  const int nemb4 = BATCH * TSTEPS * HDIM / 4;  // 4,194,304
  embed_kernel<<<nemb4 / 256, 256, 0, stream>>>(ids, table, xb, nemb4);

  float* out_last   = out;              // (64,1024)
  float* out_logits = out + 65536;      // (64,32000)
  float* out_hn     = out + 2113536;    // (2,64,1024)
  float* out_cn     = out + 2244608;    // (2,64,1024)

  for (int lyr = 0; lyr < 2; ++lyr) {
    gemm_xg_kernel<<<dim3(GDIM / BNX, (BATCH * TSTEPS) / BMX), 256, 0, stream>>>(
        xb, wihb + (size_t)lyr * GDIM * HDIM, bih + lyr * GDIM, bhh + lyr * GDIM, xg);
    unsigned* flags = sync + (size_t)lyr * 8192;
    unsigned* go    = flags + 4096;
    lstm_seq_kernel<<<NWG_SEQ, 512, 0, stream>>>(
        xg, whhb + (size_t)lyr * GDIM * HDIM, h0, h1, xb,
        out_hn + (size_t)lyr * BATCH * HDIM, out_cn + (size_t)lyr * BATCH * HDIM,
        (lyr == 1) ? out_last : nullptr, flags, go);
  }
  logits_kernel<<<VOCAB / 64, 256, 0, stream>>>(h0, Wp, bp, out_logits);
}

// Round 3
// 5598.492 us; speedup vs baseline: 2.9941x; 1.6548x over previous
//
#include <hip/hip_runtime.h>
#include <hip/hip_bf16.h>
#include <stdint.h>
#include <stddef.h>

typedef __hip_bfloat16 bf16;
typedef __attribute__((ext_vector_type(8))) short bfrag;
typedef __attribute__((ext_vector_type(4))) float ffrag;

#define HDIM 1024
#define BATCH 64
#define TSTEPS 256
#define GDIM 4096
#define VOCAB 32000
#define NWG_SEQ 128   // 128 WGs x 256 threads; WG owns 8 hidden cols (32 gate cols)

__device__ __forceinline__ float b2f(bf16 x) { return __bfloat162float(x); }
__device__ __forceinline__ bf16 f2b(float x) { return __float2bfloat16(x); }
__device__ __forceinline__ short f2bs(float x) {
  bf16 b = __float2bfloat16(x);
  return *reinterpret_cast<short*>(&b);
}
__device__ __forceinline__ float bs2f(unsigned short u) {
  union { unsigned int i; float f; } v;
  v.i = ((unsigned int)u) << 16;
  return v.f;
}
__device__ __forceinline__ ffrag mfma16(bfrag a, bfrag b, ffrag c) {
  return __builtin_amdgcn_mfma_f32_16x16x32_bf16(a, b, c, 0, 0, 0);
}
__device__ __forceinline__ float sigm(float x) { return 1.0f / (1.0f + __expf(-x)); }
__device__ __forceinline__ float tanhfast(float x) {
  float e = __expf(2.0f * x);
  return 1.0f - 2.0f / (e + 1.0f);
}

// agent-scope point-coherent 8B ops (sc1: bypass non-coherent caches, no fences)
__device__ __forceinline__ void store_u64_agent(unsigned long long* p, unsigned long long v) {
  __hip_atomic_store(p, v, __ATOMIC_RELAXED, __HIP_MEMORY_SCOPE_AGENT);
}
__device__ __forceinline__ unsigned long long load_u64_agent(const unsigned long long* p) {
  return __hip_atomic_load(p, __ATOMIC_RELAXED, __HIP_MEMORY_SCOPE_AGENT);
}

// ---------------- convert f32 -> bf16 ----------------
__global__ void convert_bf16_kernel(const float* __restrict__ src, bf16* __restrict__ dst, int n4) {
  int i = blockIdx.x * 256 + threadIdx.x;
  if (i >= n4) return;
  float4 v = reinterpret_cast<const float4*>(src)[i];
  ushort4 o;
  o.x = (unsigned short)f2bs(v.x);
  o.y = (unsigned short)f2bs(v.y);
  o.z = (unsigned short)f2bs(v.z);
  o.w = (unsigned short)f2bs(v.w);
  reinterpret_cast<ushort4*>(dst)[i] = o;
}

// ---------------- embedding gather -> bf16 ----------------
__global__ void embed_kernel(const int* __restrict__ ids, const float* __restrict__ table,
                             bf16* __restrict__ x, int n4) {
  int i = blockIdx.x * 256 + threadIdx.x;
  if (i >= n4) return;
  int row = i >> 8;   // H/4 = 256 float4 per (b,t) row
  int c4 = i & 255;
  int tok = ids[row];
  float4 v = reinterpret_cast<const float4*>(table)[(size_t)tok * 256 + c4];
  ushort4 o;
  o.x = (unsigned short)f2bs(v.x);
  o.y = (unsigned short)f2bs(v.y);
  o.z = (unsigned short)f2bs(v.z);
  o.w = (unsigned short)f2bs(v.w);
  reinterpret_cast<ushort4*>(x)[i] = o;
}

// ---------------- xg = x @ W_ih^T + b_ih + b_hh ----------------
// A: (16384,1024) bf16 K-major; W: (4096,1024) bf16 K-major.
// out xg layout: (wg, t, b, 32) -- per-recurrence-WG contiguous.
#define BMX 128
#define BNX 128
#define BKX 64

__launch_bounds__(256, 2)
__global__ void gemm_xg_kernel(const bf16* __restrict__ A,
                               const bf16* __restrict__ W,
                               const float* __restrict__ bih,
                               const float* __restrict__ bhh,
                               bf16* __restrict__ xg) {
  __shared__ bf16 As[BMX][BKX + 8];
  __shared__ bf16 Bs[BNX][BKX + 8];
  const int n0 = blockIdx.x * BNX;
  const int m0 = blockIdx.y * BMX;
  const int tid = threadIdx.x;
  const int w = tid >> 6, l = tid & 63;
  const int wm = (w >> 1) * 64, wn = (w & 1) * 64;
  const int lr = l & 15, lk = (l >> 4) * 8;

  ffrag acc[4][4];
#pragma unroll
  for (int i = 0; i < 4; ++i)
#pragma unroll
    for (int j = 0; j < 4; ++j) acc[i][j] = ffrag{0.f, 0.f, 0.f, 0.f};

  const int sr = tid >> 1, sh = (tid & 1) * 32;
  for (int kb = 0; kb < HDIM; kb += BKX) {
    __syncthreads();
    {
      const uint4* ga = reinterpret_cast<const uint4*>(&A[(size_t)(m0 + sr) * HDIM + kb + sh]);
      uint4* la = reinterpret_cast<uint4*>(&As[sr][sh]);
      la[0] = ga[0]; la[1] = ga[1]; la[2] = ga[2]; la[3] = ga[3];
      const uint4* gb = reinterpret_cast<const uint4*>(&W[(size_t)(n0 + sr) * HDIM + kb + sh]);
      uint4* lb = reinterpret_cast<uint4*>(&Bs[sr][sh]);
      lb[0] = gb[0]; lb[1] = gb[1]; lb[2] = gb[2]; lb[3] = gb[3];
    }
    __syncthreads();
#pragma unroll
    for (int ks = 0; ks < 2; ++ks) {
      const int ko = ks * 32 + lk;
      bfrag af[4], bfv[4];
#pragma unroll
      for (int i = 0; i < 4; ++i)
        af[i] = *reinterpret_cast<const bfrag*>(&As[wm + i * 16 + lr][ko]);
#pragma unroll
      for (int j = 0; j < 4; ++j)
        bfv[j] = *reinterpret_cast<const bfrag*>(&Bs[wn + j * 16 + lr][ko]);
#pragma unroll
      for (int i = 0; i < 4; ++i)
#pragma unroll
        for (int j = 0; j < 4; ++j)
          acc[i][j] = mfma16(af[i], bfv[j], acc[i][j]);
    }
  }
  const int rg = (l >> 4) * 4;
#pragma unroll
  for (int j = 0; j < 4; ++j) {
    const int n = n0 + wn + j * 16 + lr;
    const float bias = bih[n] + bhh[n];
    const int g = (n & 1023) >> 3;                 // owning recurrence WG
    const int p = ((n >> 10) << 3) | (n & 7);      // slot within WG's 32 cols
    bf16* base = xg + (size_t)g * TSTEPS * BATCH * 32;
#pragma unroll
    for (int i = 0; i < 4; ++i) {
#pragma unroll
      for (int r = 0; r < 4; ++r) {
        const int m = m0 + wm + i * 16 + rg + r;
        const int b = m >> 8, t = m & 255;   // m = b*256 + t
        base[((size_t)t * BATCH + b) * 32 + p] = f2b(acc[i][j][r] + bias);
      }
    }
  }
}

// ---------------- persistent LSTM recurrence ----------------
// 128 WGs x 256 threads (4 waves). WG g owns hidden cols j0=8g..8g+7 => 32 gate
// cols (slot p: q=p>>3, jj=p&7 -> gcol = q*1024 + j0 + jj).
// Wave w handles batch rows 16w..16w+15, both 16-col tiles of the 32 slots.
// h exchange: sc1 stores + per-WG epoch flag + all-to-all flag poll (1 hop).
__launch_bounds__(256, 1)
__global__ void lstm_seq_kernel(const bf16* __restrict__ xg,   // (wg,t,b,32)
                                const bf16* __restrict__ Whh,  // (4096,1024) bf16
                                bf16* h0, bf16* h1,            // ping-pong h
                                bf16* __restrict__ ys,         // (B,T,H) layer output
                                float* __restrict__ out_h,
                                float* __restrict__ out_c,
                                float* __restrict__ out_last,  // null except last layer
                                unsigned* __restrict__ flags) {
  __shared__ bf16 lw[32][HDIM + 8];   // W_hh rows for the 32 gate cols
  __shared__ float gx[BATCH][36];     // gate exchange (batch x 32, padded)
  const int wg = blockIdx.x;
  const int tid = threadIdx.x;
  const int w = tid >> 6, l = tid & 63;
  const int j0 = wg * 8;

  // stage this WG's 32 W_hh rows into LDS (once)
  {
    const int p = tid >> 3, li = tid & 7;
    const int gcol = (p >> 3) * HDIM + j0 + (p & 7);
    const uint4* src = reinterpret_cast<const uint4*>(&Whh[(size_t)gcol * HDIM]);
    uint4* dst = reinterpret_cast<uint4*>(&lw[p][0]);
#pragma unroll
    for (int kk = 0; kk < 16; ++kk) dst[li + kk * 8] = src[li + kk * 8];
  }

  // elementwise ownership: tid<128 -> batch eb, 4 cols starting j0+ej
  const int eb = tid >> 1;
  const int ej = (tid & 1) * 4;
  float c0 = 0.f, c1 = 0.f, c2 = 0.f, c3 = 0.f;

  // init h0 slice (point-coherent stores)
  if (tid < 128) {
    store_u64_agent((unsigned long long*)&h0[(size_t)eb * HDIM + j0 + ej], 0ull);
    __builtin_amdgcn_s_waitcnt(0);
  }
  __syncthreads();
  if (tid == 0)
    __hip_atomic_store(&flags[wg * 32], 1u, __ATOMIC_RELAXED, __HIP_MEMORY_SCOPE_AGENT);
  if (tid < 128) {
    while (__hip_atomic_load(&flags[tid * 32], __ATOMIC_RELAXED, __HIP_MEMORY_SCOPE_AGENT) < 1u)
      __builtin_amdgcn_s_sleep(1);
  }
  __syncthreads();
  __builtin_amdgcn_sched_barrier(0);

  const int lr = l & 15, lk = (l >> 4) * 8;
  const int rg = (l >> 4) * 4;
  const bf16* xgw = xg + (size_t)wg * TSTEPS * BATCH * 32;

  // prefetch xg(t=0): this thread's 8 values (4 rows x 2 col-tiles)
  unsigned short xn[8];
  {
    const unsigned short* xt = (const unsigned short*)xgw;
#pragma unroll
    for (int r = 0; r < 4; ++r) {
      const int b = 16 * w + rg + r;
      xn[r]     = xt[b * 32 + lr];
      xn[4 + r] = xt[b * 32 + 16 + lr];
    }
  }

  for (int t = 0; t < TSTEPS; ++t) {
    const bf16* hin  = (t & 1) ? h1 : h0;
    bf16*       hout = (t & 1) ? h0 : h1;
    ffrag acc0 = ffrag{0.f, 0.f, 0.f, 0.f};
    ffrag acc1 = ffrag{0.f, 0.f, 0.f, 0.f};
    const unsigned long long* hrow =
        (const unsigned long long*)&hin[(size_t)(16 * w + lr) * HDIM];
#pragma unroll 8
    for (int ks = 0; ks < 32; ++ks) {
      const int off = (ks * 32 + lk) >> 2;   // ulong index (4 bf16 each)
      union { unsigned long long u[2]; bfrag f; } au;
      au.u[0] = load_u64_agent(hrow + off);
      au.u[1] = load_u64_agent(hrow + off + 1);
      bfrag b0 = *reinterpret_cast<const bfrag*>(&lw[lr][ks * 32 + lk]);
      bfrag b1 = *reinterpret_cast<const bfrag*>(&lw[16 + lr][ks * 32 + lk]);
      acc0 = mfma16(au.f, b0, acc0);
      acc1 = mfma16(au.f, b1, acc1);
    }
    // gates into LDS (add prefetched xg)
#pragma unroll
    for (int r = 0; r < 4; ++r) {
      const int b = 16 * w + rg + r;
      gx[b][lr]      = acc0[r] + bs2f(xn[r]);
      gx[b][16 + lr] = acc1[r] + bs2f(xn[4 + r]);
    }
    // prefetch next step's xg (independent of h) -- hides HBM latency
    {
      const int tn = (t + 1 < TSTEPS) ? t + 1 : t;
      const unsigned short* xt = (const unsigned short*)(xgw + (size_t)tn * BATCH * 32);
#pragma unroll
      for (int r = 0; r < 4; ++r) {
        const int b = 16 * w + rg + r;
        xn[r]     = xt[b * 32 + lr];
        xn[4 + r] = xt[b * 32 + 16 + lr];
      }
    }
    __syncthreads();   // gx ready
    if (tid < 128) {
      float hnew[4];
#pragma unroll
      for (int m = 0; m < 4; ++m) {
        const int jc = ej + m;
        const float gi = gx[eb][0 * 8 + jc];
        const float gf = gx[eb][1 * 8 + jc];
        const float gg = gx[eb][2 * 8 + jc];
        const float go = gx[eb][3 * 8 + jc];
        const float iv = sigm(gi), fv = sigm(gf), gv = tanhfast(gg), ov = sigm(go);
        float cr = (m == 0) ? c0 : (m == 1) ? c1 : (m == 2) ? c2 : c3;
        cr = fv * cr + iv * gv;
        if (m == 0) c0 = cr; else if (m == 1) c1 = cr; else if (m == 2) c2 = cr; else c3 = cr;
        hnew[m] = ov * tanhfast(cr);
      }
      union { unsigned short s[4]; unsigned long long u; } pk;
#pragma unroll
      for (int m = 0; m < 4; ++m) pk.s[m] = (unsigned short)f2bs(hnew[m]);
      store_u64_agent((unsigned long long*)&hout[(size_t)eb * HDIM + j0 + ej], pk.u);
      *(unsigned long long*)&ys[((size_t)eb * TSTEPS + t) * HDIM + j0 + ej] = pk.u;
      if (t == TSTEPS - 1) {
        float4 hv = {hnew[0], hnew[1], hnew[2], hnew[3]};
        float4 cv = {c0, c1, c2, c3};
        *reinterpret_cast<float4*>(&out_h[(size_t)eb * HDIM + j0 + ej]) = hv;
        *reinterpret_cast<float4*>(&out_c[(size_t)eb * HDIM + j0 + ej]) = cv;
        if (out_last) *reinterpret_cast<float4*>(&out_last[(size_t)eb * HDIM + j0 + ej]) = hv;
      }
      __builtin_amdgcn_s_waitcnt(0);   // h stores acked at coherence point
    }
    if (t + 1 < TSTEPS) {
      __syncthreads();                 // all waves' stores drained
      const unsigned ep = (unsigned)(t + 2);
      if (tid == 0)
        __hip_atomic_store(&flags[wg * 32], ep, __ATOMIC_RELAXED, __HIP_MEMORY_SCOPE_AGENT);
      if (tid < 128) {
        while (__hip_atomic_load(&flags[tid * 32], __ATOMIC_RELAXED, __HIP_MEMORY_SCOPE_AGENT) < ep)
          __builtin_amdgcn_s_sleep(1);
      }
      __syncthreads();
      __builtin_amdgcn_sched_barrier(0);
    }
  }
}

// ---------------- logits = h_T @ W_proj^T + b_proj ----------------
__launch_bounds__(256, 2)
__global__ void logits_kernel(const bf16* __restrict__ hfin,  // (64,1024) bf16
                              const float* __restrict__ Wp,   // (32000,1024) f32
                              const float* __restrict__ bp,
                              float* __restrict__ out) {      // (64,32000)
  const int tid = threadIdx.x;
  const int w = tid >> 6, l = tid & 63;
  const int lr = l & 15, lk = (l >> 4) * 8;
  const int col = blockIdx.x * 64 + w * 16 + lr;
  const float* wrow = &Wp[(size_t)col * HDIM];
  ffrag acc[4];
#pragma unroll
  for (int i = 0; i < 4; ++i) acc[i] = ffrag{0.f, 0.f, 0.f, 0.f};
#pragma unroll 2
  for (int ks = 0; ks < 32; ++ks) {
    const int k = ks * 32 + lk;
    float4 wa = *reinterpret_cast<const float4*>(&wrow[k]);
    float4 wb = *reinterpret_cast<const float4*>(&wrow[k + 4]);
    bfrag bv;
    bv[0] = f2bs(wa.x); bv[1] = f2bs(wa.y); bv[2] = f2bs(wa.z); bv[3] = f2bs(wa.w);
    bv[4] = f2bs(wb.x); bv[5] = f2bs(wb.y); bv[6] = f2bs(wb.z); bv[7] = f2bs(wb.w);
#pragma unroll
    for (int i = 0; i < 4; ++i) {
      bfrag av = *reinterpret_cast<const bfrag*>(&hfin[(size_t)(i * 16 + lr) * HDIM + k]);
      acc[i] = mfma16(av, bv, acc[i]);
    }
  }
  const float bias = bp[col];
#pragma unroll
  for (int i = 0; i < 4; ++i) {
#pragma unroll
    for (int r = 0; r < 4; ++r) {
      const int b = i * 16 + (l >> 4) * 4 + r;
      out[(size_t)b * VOCAB + col] = acc[i][r] + bias;
    }
  }
}

extern "C" void kernel_launch(void* const* d_in, const int* in_sizes, int n_in,
                              void* d_out, int out_size, void* d_ws, size_t ws_size,
                              hipStream_t stream) {
  const int*   ids   = (const int*)d_in[0];
  const float* table = (const float*)d_in[1];
  const float* Wih   = (const float*)d_in[2];
  const float* Whh   = (const float*)d_in[3];
  const float* bih   = (const float*)d_in[4];
  const float* bhh   = (const float*)d_in[5];
  const float* Wp    = (const float*)d_in[6];
  const float* bp    = (const float*)d_in[7];
  float* out = (float*)d_out;

  char* ws = (char*)d_ws;
  const size_t OFF_XG  = 0;
  const size_t OFF_X   = OFF_XG  + (size_t)NWG_SEQ * TSTEPS * BATCH * 32 * 2;  // 128 MB
  const size_t OFF_WIH = OFF_X   + (size_t)BATCH * TSTEPS * HDIM * 2;
  const size_t OFF_WHH = OFF_WIH + (size_t)2 * GDIM * HDIM * 2;
  const size_t OFF_SYNC= OFF_WHH + (size_t)2 * GDIM * HDIM * 2;
  const size_t OFF_H0  = OFF_SYNC+ (size_t)65536;
  const size_t OFF_H1  = OFF_H0  + (size_t)BATCH * HDIM * 2;

  bf16* xg    = (bf16*)(ws + OFF_XG);
  bf16* xb    = (bf16*)(ws + OFF_X);
  bf16* wihb  = (bf16*)(ws + OFF_WIH);
  bf16* whhb  = (bf16*)(ws + OFF_WHH);
  unsigned* sync = (unsigned*)(ws + OFF_SYNC);
  bf16* h0    = (bf16*)(ws + OFF_H0);
  bf16* h1    = (bf16*)(ws + OFF_H1);

  (void)hipMemsetAsync(sync, 0, 65536, stream);

  const int nconv4 = 2 * GDIM * HDIM / 4;
  convert_bf16_kernel<<<nconv4 / 256, 256, 0, stream>>>(Wih, wihb, nconv4);
  convert_bf16_kernel<<<nconv4 / 256, 256, 0, stream>>>(Whh, whhb, nconv4);
  const int nemb4 = BATCH * TSTEPS * HDIM / 4;
  embed_kernel<<<nemb4 / 256, 256, 0, stream>>>(ids, table, xb, nemb4);

  float* out_last   = out;              // (64,1024)
  float* out_logits = out + 65536;      // (64,32000)
  float* out_hn     = out + 2113536;    // (2,64,1024)
  float* out_cn     = out + 2244608;    // (2,64,1024)

  for (int lyr = 0; lyr < 2; ++lyr) {
    gemm_xg_kernel<<<dim3(GDIM / BNX, (BATCH * TSTEPS) / BMX), 256, 0, stream>>>(
        xb, wihb + (size_t)lyr * GDIM * HDIM, bih + lyr * GDIM, bhh + lyr * GDIM, xg);
    unsigned* flags = sync + (size_t)lyr * 8192;
    lstm_seq_kernel<<<NWG_SEQ, 256, 0, stream>>>(
        xg, whhb + (size_t)lyr * GDIM * HDIM, h0, h1, xb,
        out_hn + (size_t)lyr * BATCH * HDIM, out_cn + (size_t)lyr * BATCH * HDIM,
        (lyr == 1) ? out_last : nullptr, flags);
  }
  logits_kernel<<<VOCAB / 64, 256, 0, stream>>>(h0, Wp, bp, out_logits);
}